// Round 13
// baseline (114.258 us; speedup 1.0000x reference)
//
#include <hip/hip_runtime.h>
#include <math.h>

// N=2, K=20 -> 40 images; C=64 channels; 16x16 images (256 px).
#define NIMG 40
#define PXI  256
#define CH   64
#define SB_ELEM (NIMG * PXI * CH)   // 655360 elems per activation tensor
#define ZEROOFF 32768u              // byte offset of zero slot (stage-conv paths)

typedef __bf16 bf16x8 __attribute__((ext_vector_type(8)));
typedef float  f32x4  __attribute__((ext_vector_type(4)));

static __device__ __forceinline__ unsigned short f2bf(float f) {
    unsigned u = __builtin_bit_cast(unsigned, f);
    u += 0x7fffu + ((u >> 16) & 1u);          // RNE
    return (unsigned short)(u >> 16);
}
static __device__ __forceinline__ unsigned cvtpk(float lo, float hi) {
    unsigned r;
    asm("v_cvt_pk_bf16_f32 %0, %1, %2" : "=v"(r) : "v"(lo), "v"(hi));
    return r;
}
static __device__ __forceinline__ float bfu2f(unsigned hs) {  // bf16 bits in low 16
    unsigned u = (hs & 0xffffu) << 16;
    return __builtin_bit_cast(float, u);
}
static __device__ __forceinline__ float sigm(float x) {
    return 1.f / (1.f + __expf(-x));
}

// ===========================================================================
// Weight layout (coalesced): uint4 index = ((kk*2+kh)*4 + oct)*64 + lane;
// element j: oc = oct*16 + (lane&15), ci = (kh*4+(lane>>4))*8 + j.
// Stage-conv LDS Z: pixel pix, group g at byte pix*128 + ((g^(pix&7))<<4).
// Pair LDS Z: LOCAL rows (yloc 0..9 = global r0-1..r0+8, borders zeroed):
//   byte = src*20480 + yloc*2048 + xx*128 + ((g^(xx&7))<<4).   (40960 B)
//
// WORKSPACE LIVENESS INVARIANT (G16): partials slabs 0..9 overlay
// Xpad/h/p1/pg1; ALL consumers of those (map, stage-1, stage-2 convs) must
// complete in launches BEFORE pair_mfma_k. Do NOT fuse stage-2 into the pair
// kernel (R8/R9 race).
// ===========================================================================

// ---------------------------------------------------------------------------
// Stage-conv core (R6/R7 proven): wave computes R rows x O oc-tiles.
// ---------------------------------------------------------------------------
template<int R, int O>
static __device__ __forceinline__ void conv_core(const char* __restrict__ zb,
                                                 const uint4* __restrict__ Wt,
                                                 int octg0, int r0, int lane,
                                                 const unsigned base[2][3],
                                                 const unsigned step[3],
                                                 f32x4 (&acc)[R][O])
{
#pragma unroll
    for (int kx = 0; kx < 3; ++kx)
#pragma unroll
        for (int kh = 0; kh < 2; ++kh) {
            uint4 w[3][O];
#pragma unroll
            for (int ky = 0; ky < 3; ++ky)
#pragma unroll
                for (int o = 0; o < O; ++o)
                    w[ky][o] = Wt[(((ky * 3 + kx) * 2 + kh) * 4 + octg0 + o) * 64 + lane];
#pragma unroll
            for (int dd = 0; dd < R + 2; ++dd) {
                const int ri = r0 + dd - 1;          // input row (wave-uniform)
                if (ri >= 0 && ri < 16) {
                    uint4 a = *(const uint4*)(zb + (base[kh][kx] + (unsigned)ri * step[kx]));
                    bf16x8 af = __builtin_bit_cast(bf16x8, a);
#pragma unroll
                    for (int ky = 0; ky < 3; ++ky) {
                        const int orow = dd - ky;
                        if (orow < 0 || orow >= R) continue;
#pragma unroll
                        for (int o = 0; o < O; ++o)
                            acc[orow][o] = __builtin_amdgcn_mfma_f32_16x16x32_bf16(
                                af, __builtin_bit_cast(bf16x8, w[ky][o]), acc[orow][o], 0, 0, 0);
                    }
                }
            }
        }
}

static __device__ __forceinline__ void make_base(unsigned base[2][3], unsigned step[3],
                                                 int l15, int l4)
{
#pragma unroll
    for (int kx = 0; kx < 3; ++kx) {
        const int xi = l15 + kx - 1;
        const bool valid = (unsigned)xi < 16u;
        step[kx] = valid ? 2048u : 0u;
#pragma unroll
        for (int kh = 0; kh < 2; ++kh) {
            const int g = kh * 4 + l4;
            base[kh][kx] = valid ? (unsigned)(xi * 128 + (((g ^ (xi & 7))) << 4))
                                 : ZEROOFF;
        }
    }
}

// pair variant: invalid-x lanes read their own center column (2-way conflict
// is free per m136) and get the value AND'ed to zero via xmask. (R11-proven:
// bank conflicts -> 0.)
static __device__ __forceinline__ void make_base_pair(unsigned colbase[2][3], unsigned xmask[3],
                                                      int l15, int l4)
{
#pragma unroll
    for (int kx = 0; kx < 3; ++kx) {
        const int xi = l15 + kx - 1;
        const bool valid = (unsigned)xi < 16u;
        xmask[kx] = valid ? 0xFFFFFFFFu : 0u;
        const int xe = valid ? xi : l15;     // center column is always valid
#pragma unroll
        for (int kh = 0; kh < 2; ++kh) {
            const int g = kh * 4 + l4;
            colbase[kh][kx] = (unsigned)(xe * 128 + (((g ^ (xe & 7))) << 4));
        }
    }
}

// ---------------------------------------------------------------------------
// Stage convs (map + stage1 + stage2): 256 thr = 4 waves, grid (img, desc, half).
// ---------------------------------------------------------------------------
struct ConvDesc {
    const uint4* X;
    const uint4* W;
    const float* bias;      // nullptr -> no bias
    unsigned short* out;
    int relu;
};
struct ConvBatch { ConvDesc d[6]; };

__global__ __launch_bounds__(256)
void conv_mfma_k(ConvBatch cb)
{
    __shared__ uint4 Z[2049];
    const ConvDesc d = cb.d[blockIdx.y];
    const int img = blockIdx.x;
    const int tid = threadIdx.x;

    const uint4* Xi = d.X + img * 2048;
#pragma unroll
    for (int i = 0; i < 8; ++i) {
        int u = i * 256 + tid;
        int px = u >> 3, g = u & 7;
        Z[px * 8 + (g ^ (px & 7))] = Xi[u];
    }
    if (tid == 0) { uint4 z4 = {0u, 0u, 0u, 0u}; Z[2048] = z4; }
    __syncthreads();

    const int lane = tid & 63, wv = tid >> 6;
    const int l15 = lane & 15, l4 = lane >> 4;
    const int rg = wv & 1, op = wv >> 1;
    const int r0 = blockIdx.z * 8 + rg * 4;

    unsigned base[2][3], step[3];
    make_base(base, step, l15, l4);

    f32x4 acc[4][2];
    const f32x4 zz = {0.f, 0.f, 0.f, 0.f};
#pragma unroll
    for (int r = 0; r < 4; ++r)
#pragma unroll
        for (int o = 0; o < 2; ++o) acc[r][o] = zz;

    conv_core<4, 2>((const char*)Z, d.W, op * 2, r0, lane, base, step, acc);

#pragma unroll
    for (int o = 0; o < 2; ++o) {
        const int oc = (op * 2 + o) * 16 + l15;
        const float b = d.bias ? d.bias[oc] : 0.f;
#pragma unroll
        for (int r = 0; r < 4; ++r)
#pragma unroll
            for (int e = 0; e < 4; ++e) {
                float v = acc[r][o][e] + b;
                if (d.relu) v = fmaxf(v, 0.f);
                const int px = (r0 + r) * 16 + l4 * 4 + e;
                d.out[(img * PXI + px) * CH + oc] = f2bf(v);
            }
    }
}

// ---------------------------------------------------------------------------
// Pair conv core (R10 wave shape, local-row staging): wave = 2 rows x 4 octs
// x 2 sources. Per (kh,kk): 4 coalesced 1KB weight frags; per r one addr;
// 2 LDS reads feed 8 MFMAs. No y-branch (rows pre-zeroed). x-border via
// value-AND with xmask.
// ---------------------------------------------------------------------------
static __device__ __forceinline__ void conv_dual(const char* __restrict__ zb,
                                                 const uint4* __restrict__ Wt,
                                                 int rp, int lane,
                                                 const unsigned colbase[2][3],
                                                 const unsigned xmask[3],
                                                 f32x4 acc[2][2][4])
{
#pragma unroll
    for (int kh = 0; kh < 2; ++kh)
#pragma unroll
        for (int ky = 0; ky < 3; ++ky)
#pragma unroll
            for (int kx = 0; kx < 3; ++kx) {
                const int kk = ky * 3 + kx;
                bf16x8 bf[4];
#pragma unroll
                for (int oct = 0; oct < 4; ++oct)
                    bf[oct] = __builtin_bit_cast(bf16x8,
                        Wt[((kk * 2 + kh) * 4 + oct) * 64 + lane]);
#pragma unroll
                for (int r = 0; r < 2; ++r) {
                    const int yloc = rp * 2 + r + ky;          // 0..9, always valid
                    const unsigned addr = colbase[kh][kx] + (unsigned)yloc * 2048u;
                    uint4 a0 = *(const uint4*)(zb + addr);
                    uint4 a1 = *(const uint4*)(zb + addr + 20480u);
                    const unsigned m = xmask[kx];
                    a0.x &= m; a0.y &= m; a0.z &= m; a0.w &= m;
                    a1.x &= m; a1.y &= m; a1.z &= m; a1.w &= m;
                    bf16x8 f0 = __builtin_bit_cast(bf16x8, a0);
                    bf16x8 f1 = __builtin_bit_cast(bf16x8, a1);
#pragma unroll
                    for (int oct = 0; oct < 4; ++oct) {
                        acc[0][r][oct] = __builtin_amdgcn_mfma_f32_16x16x32_bf16(
                            f0, bf[oct], acc[0][r][oct], 0, 0, 0);
                        acc[1][r][oct] = __builtin_amdgcn_mfma_f32_16x16x32_bf16(
                            f1, bf[oct], acc[1][r][oct], 0, 0, 0);
                    }
                }
            }
}

static __device__ __forceinline__ uint4 relu_add4(uint4 a, uint4 b) {
    uint4 o;
    unsigned* ap = &a.x; unsigned* bp = &b.x; unsigned* op2 = &o.x;
#pragma unroll
    for (int w = 0; w < 4; ++w) {
        float a0 = __builtin_bit_cast(float, ap[w] << 16);
        float a1 = __builtin_bit_cast(float, ap[w] & 0xffff0000u);
        float b0 = __builtin_bit_cast(float, bp[w] << 16);
        float b1 = __builtin_bit_cast(float, bp[w] & 0xffff0000u);
        op2[w] = cvtpk(fmaxf(a0 + b0, 0.f), fmaxf(a1 + b1, 0.f));
    }
    return o;
}

// ---------------------------------------------------------------------------
// Pair kernel: grid 800 = (imgb, s, half), 256 thr = 4 waves (wave = rp).
// Dual-source 10-row LDS (40960 B) -> 4 blocks/CU, full 256-CU coverage.
// odd s runs gate pass first (anti-convoy stagger).
// ---------------------------------------------------------------------------
__global__ __launch_bounds__(256)
void pair_mfma_k(const uint4* __restrict__ Abf, const uint4* __restrict__ Bbf,
                 const uint4* __restrict__ Agbf, const uint4* __restrict__ Bgbf,
                 const uint4* __restrict__ W2, const uint4* __restrict__ Wg2,
                 const float* __restrict__ b2, const float* __restrict__ bg2,
                 unsigned short* __restrict__ partials)
{
    __shared__ uint4 Z[2560];                // 40960 B
    const char* zb = (const char*)Z;
    const int bx0 = blockIdx.x;
    const int tid = threadIdx.x;
    const int lane = tid & 63, rp = tid >> 6;
    const int l15 = lane & 15, l4 = lane >> 4;

    // XCD-chunked bijective swizzle (800 % 8 == 0)
    const int bi   = (bx0 & 7) * 100 + (bx0 >> 3);
    const int imgb = bi / 20;
    const int rem  = bi % 20;
    const int s    = rem >> 1;
    const int half = rem & 1;
    const int n    = imgb / 20;
    const int gf   = s & 1;                  // gate-first stagger
    const int imga0 = n * 20 + s * 2;
    const int r0   = half * 8;

    const uint4* A1; const uint4* B1; const uint4* Wp1;
    const uint4* A2; const uint4* B2; const uint4* Wp2;
    if (!gf) { A1 = Abf  + imgb * 2048; B1 = Bbf  + imga0 * 2048; Wp1 = W2;
               A2 = Agbf + imgb * 2048; B2 = Bgbf + imga0 * 2048; Wp2 = Wg2; }
    else     { A1 = Agbf + imgb * 2048; B1 = Bgbf + imga0 * 2048; Wp1 = Wg2;
               A2 = Abf  + imgb * 2048; B2 = Bbf  + imga0 * 2048; Wp2 = W2; }

    // ---- build pass-1 Z (both sources, rows r0-1..r0+8, borders zeroed) ----
#pragma unroll
    for (int i = 0; i < 10; ++i) {
        int u = i * 256 + tid;               // 0..2559
        int src = (u >= 1280) ? 1 : 0;
        int v = u - src * 1280;              // 0..1279
        int yloc = v >> 7;
        int w = v & 127;
        int xx = w >> 3, g = w & 7;
        int yy = r0 - 1 + yloc;
        uint4 val = {0u, 0u, 0u, 0u};
        if ((unsigned)yy < 16u) {
            int idx = (yy * 16 + xx) * 8 + g;
            const uint4* Bp = src ? (B1 + 2048) : B1;
            val = relu_add4(A1[idx], Bp[idx]);
        }
        Z[src * 1280 + yloc * 128 + xx * 8 + (g ^ (xx & 7))] = val;
    }
    __syncthreads();

    unsigned colbase[2][3], xmask[3];
    make_base_pair(colbase, xmask, l15, l4);

    const f32x4 zz = {0.f, 0.f, 0.f, 0.f};
    f32x4 acc[2][2][4];
#pragma unroll
    for (int sc = 0; sc < 2; ++sc)
#pragma unroll
        for (int r = 0; r < 2; ++r)
#pragma unroll
            for (int o = 0; o < 4; ++o) acc[sc][r][o] = zz;

    __builtin_amdgcn_s_setprio(1);
    conv_dual(zb, Wp1, rp, lane, colbase, xmask, acc);
    __builtin_amdgcn_s_setprio(0);

    float bmv[4], bgv[4];
#pragma unroll
    for (int oct = 0; oct < 4; ++oct) {
        bmv[oct] = b2[oct * 16 + l15];
        bgv[oct] = bg2[oct * 16 + l15];
    }

    // ---- stash pass-1 result as bf16 ----
    unsigned st[2][2][4][2];
    if (!gf) {
#pragma unroll
        for (int sc = 0; sc < 2; ++sc)
#pragma unroll
            for (int r = 0; r < 2; ++r)
#pragma unroll
                for (int oct = 0; oct < 4; ++oct) {
                    st[sc][r][oct][0] = cvtpk(acc[sc][r][oct][0] + bmv[oct],
                                              acc[sc][r][oct][1] + bmv[oct]);
                    st[sc][r][oct][1] = cvtpk(acc[sc][r][oct][2] + bmv[oct],
                                              acc[sc][r][oct][3] + bmv[oct]);
                }
    } else {
#pragma unroll
        for (int sc = 0; sc < 2; ++sc)
#pragma unroll
            for (int r = 0; r < 2; ++r)
#pragma unroll
                for (int oct = 0; oct < 4; ++oct) {
                    st[sc][r][oct][0] = cvtpk(sigm(acc[sc][r][oct][0] + bgv[oct]),
                                              sigm(acc[sc][r][oct][1] + bgv[oct]));
                    st[sc][r][oct][1] = cvtpk(sigm(acc[sc][r][oct][2] + bgv[oct]),
                                              sigm(acc[sc][r][oct][3] + bgv[oct]));
                }
    }
    __syncthreads();   // all reads of Z done

    // ---- build pass-2 Z ----
#pragma unroll
    for (int i = 0; i < 10; ++i) {
        int u = i * 256 + tid;
        int src = (u >= 1280) ? 1 : 0;
        int v = u - src * 1280;
        int yloc = v >> 7;
        int w = v & 127;
        int xx = w >> 3, g = w & 7;
        int yy = r0 - 1 + yloc;
        uint4 val = {0u, 0u, 0u, 0u};
        if ((unsigned)yy < 16u) {
            int idx = (yy * 16 + xx) * 8 + g;
            const uint4* Bp = src ? (B2 + 2048) : B2;
            val = relu_add4(A2[idx], Bp[idx]);
        }
        Z[src * 1280 + yloc * 128 + xx * 8 + (g ^ (xx & 7))] = val;
    }
    __syncthreads();

#pragma unroll
    for (int sc = 0; sc < 2; ++sc)
#pragma unroll
        for (int r = 0; r < 2; ++r)
#pragma unroll
            for (int o = 0; o < 4; ++o) acc[sc][r][o] = zz;

    __builtin_amdgcn_s_setprio(1);
    conv_dual(zb, Wp2, rp, lane, colbase, xmask, acc);
    __builtin_amdgcn_s_setprio(0);

    // ---- combine + store: partials[s][img][oc][px] ----
    const int pbase = (s * NIMG + imgb) * (PXI * CH);
#pragma unroll
    for (int r = 0; r < 2; ++r)
#pragma unroll
        for (int oct = 0; oct < 4; ++oct) {
            float o[4] = {0.f, 0.f, 0.f, 0.f};
            if (!gf) {
#pragma unroll
                for (int sc = 0; sc < 2; ++sc)
#pragma unroll
                    for (int e = 0; e < 4; ++e) {
                        float gt = acc[sc][r][oct][e] + bgv[oct];
                        float m  = bfu2f(st[sc][r][oct][e >> 1] >> ((e & 1) * 16));
                        o[e] += m * sigm(gt);
                    }
            } else {
#pragma unroll
                for (int sc = 0; sc < 2; ++sc)
#pragma unroll
                    for (int e = 0; e < 4; ++e) {
                        float m  = acc[sc][r][oct][e] + bmv[oct];
                        float sg = bfu2f(st[sc][r][oct][e >> 1] >> ((e & 1) * 16));
                        o[e] += m * sg;
                    }
            }
            uint2 pkd;
            pkd.x = cvtpk(o[0], o[1]);
            pkd.y = cvtpk(o[2], o[3]);
            const int px0 = (r0 + rp * 2 + r) * 16 + l4 * 4;
            const int oc  = oct * 16 + l15;
            *(uint2*)&partials[pbase + oc * PXI + px0] = pkd;
        }
}

// ---------------------------------------------------------------------------
// Merged prep: weight repack (coalesced layout) + X padding.
// ---------------------------------------------------------------------------
struct WPrep { const float* src; unsigned short* dst; int cin_src; int cioff; int nvalid; };
struct WPrepBatch { WPrep w[11]; };

__global__ __launch_bounds__(256)
void prep_k(WPrepBatch wb, const float* __restrict__ x, const float* __restrict__ t,
            unsigned short* __restrict__ Xpad)
{
    const int bx = blockIdx.x;
    if (bx < 1584) {
        const WPrep p = wb.w[bx / 144];
        const int e = (bx % 144) * 256 + threadIdx.x;   // 0..36863
        const int j = e & 7;
        const int u4 = e >> 3;
        const int lane = u4 & 63;
        const int oct = (u4 >> 6) & 3;
        const int kh  = (u4 >> 8) & 1;
        const int kk  = u4 >> 9;
        const int oc  = oct * 16 + (lane & 15);
        const int ci  = (kh * 4 + (lane >> 4)) * 8 + j;
        float v = 0.f;
        if (ci < p.nvalid)
            v = p.src[(oc * p.cin_src + p.cioff + ci) * 9 + kk];
        p.dst[e] = f2bf(v);
    } else {
        const int idx = (bx - 1584) * 256 + threadIdx.x;  // 0..655359
        const int img = idx >> 14;
        const int px  = (idx >> 6) & 255;
        const int ch  = idx & 63;
        float v;
        if (ch == 0)       v = t[0];
        else if (ch <= 32) v = x[((img * 32) + (ch - 1)) * PXI + px];
        else               v = 0.f;
        Xpad[idx] = f2bf(v);
    }
}

// ---------------------------------------------------------------------------
// Final: out[img][oc][px] = u*sigmoid(ug) + (sum_s partials[s])/19.
// ---------------------------------------------------------------------------
__global__ __launch_bounds__(512)
void final_k(const unsigned short* __restrict__ u_lin,
             const unsigned short* __restrict__ ug_lin,
             const unsigned short* __restrict__ P,
             float* __restrict__ out)
{
    __shared__ float buf[PXI * 65];
    const int img = blockIdx.x;
    const int tid = threadIdx.x;

#pragma unroll
    for (int i = 0; i < 32; ++i) {
        const int idx = i * 512 + tid;          // [px][oc], oc innermost
        const int px = idx >> 6, oc = idx & 63;
        const float u = bfu2f(u_lin[img * (PXI * CH) + idx]);
        const float g = bfu2f(ug_lin[img * (PXI * CH) + idx]);
        buf[px * 65 + oc] = u * sigm(g);
    }
    __syncthreads();
#pragma unroll
    for (int i = 0; i < 32; ++i) {
        const int j = i * 512 + tid;            // [oc][px], px innermost
        const int oc = j >> 8, px = j & 255;
        float ssum = 0.f;
#pragma unroll
        for (int sl = 0; sl < 10; ++sl)
            ssum += bfu2f(P[(sl * NIMG + img) * (PXI * CH) + j]);
        out[img * (PXI * CH) + j] = buf[px * 65 + oc] + ssum * (1.f / 19.f);
    }
}

// ---------------------------------------------------------------------------
extern "C" void kernel_launch(void* const* d_in, const int* in_sizes, int n_in,
                              void* d_out, int out_size, void* d_ws, size_t ws_size,
                              hipStream_t stream)
{
    const float* t     = (const float*)d_in[0];
    const float* x     = (const float*)d_in[1];
    const float* w_map = (const float*)d_in[2];
    const float* b_map = (const float*)d_in[3];
    const float* w_u1  = (const float*)d_in[4];
    const float* b_u1  = (const float*)d_in[5];
    const float* w_u2  = (const float*)d_in[6];
    const float* b_u2  = (const float*)d_in[7];
    const float* w_ug1 = (const float*)d_in[8];
    const float* b_ug1 = (const float*)d_in[9];
    const float* w_ug2 = (const float*)d_in[10];
    const float* b_ug2 = (const float*)d_in[11];
    const float* w_b1  = (const float*)d_in[12];
    const float* b_b1  = (const float*)d_in[13];
    const float* w_b2  = (const float*)d_in[14];
    const float* b_b2  = (const float*)d_in[15];
    const float* w_bg1 = (const float*)d_in[16];
    const float* b_bg1 = (const float*)d_in[17];
    const float* w_bg2 = (const float*)d_in[18];
    const float* b_bg2 = (const float*)d_in[19];

    float* out = (float*)d_out;
    char* ws = (char*)d_ws;

    const size_t ABYTES = (size_t)SB_ELEM * 2;      // 1,310,720 B per bf16 tensor

    // Partials (10 bf16 slabs) overlay slabs 0..9; Xpad/h/p1/pg1 live in the
    // first 4 and are dead before pair_mfma_k runs (ALL their consumers --
    // map, stage-1, stage-2 -- are in earlier launches; see invariant above).
    unsigned short* partials = (unsigned short*)(ws);
    unsigned short* Xpad   = (unsigned short*)(ws + 0 * ABYTES);
    unsigned short* h      = (unsigned short*)(ws + 1 * ABYTES);
    unsigned short* p1     = (unsigned short*)(ws + 2 * ABYTES);
    unsigned short* pg1    = (unsigned short*)(ws + 3 * ABYTES);
    unsigned short* u_lin  = (unsigned short*)(ws + 10 * ABYTES);
    unsigned short* ug_lin = (unsigned short*)(ws + 11 * ABYTES);
    unsigned short* Abuf   = (unsigned short*)(ws + 12 * ABYTES);
    unsigned short* Bbuf   = (unsigned short*)(ws + 13 * ABYTES);
    unsigned short* Agbuf  = (unsigned short*)(ws + 14 * ABYTES);
    unsigned short* Bgbuf  = (unsigned short*)(ws + 15 * ABYTES);
    char* wbase = ws + 16 * ABYTES;                 // ~21 MB
    const size_t WBYTES = 9 * 64 * 64 * 2;          // 73,728 B per weight tensor
    unsigned short* Wmap  = (unsigned short*)(wbase + 0 * WBYTES);
    unsigned short* Wu1   = (unsigned short*)(wbase + 1 * WBYTES);
    unsigned short* Wu2   = (unsigned short*)(wbase + 2 * WBYTES);
    unsigned short* Wug1  = (unsigned short*)(wbase + 3 * WBYTES);
    unsigned short* Wug2  = (unsigned short*)(wbase + 4 * WBYTES);
    unsigned short* Wb1a  = (unsigned short*)(wbase + 5 * WBYTES);
    unsigned short* Wb1b  = (unsigned short*)(wbase + 6 * WBYTES);
    unsigned short* Wbg1a = (unsigned short*)(wbase + 7 * WBYTES);
    unsigned short* Wbg1b = (unsigned short*)(wbase + 8 * WBYTES);
    unsigned short* Wb2   = (unsigned short*)(wbase + 9 * WBYTES);
    unsigned short* Wbg2  = (unsigned short*)(wbase + 10 * WBYTES);

    // --- prep: weights repack + Xpad build (one launch) ---
    WPrepBatch wb;
    wb.w[0]  = { w_map, Wmap,  33,  0, 33 };
    wb.w[1]  = { w_u1,  Wu1,   64,  0, 64 };
    wb.w[2]  = { w_u2,  Wu2,   64,  0, 64 };
    wb.w[3]  = { w_ug1, Wug1,  64,  0, 64 };
    wb.w[4]  = { w_ug2, Wug2,  64,  0, 64 };
    wb.w[5]  = { w_b1,  Wb1a, 128,  0, 64 };
    wb.w[6]  = { w_b1,  Wb1b, 128, 64, 64 };
    wb.w[7]  = { w_bg1, Wbg1a,128,  0, 64 };
    wb.w[8]  = { w_bg1, Wbg1b,128, 64, 64 };
    wb.w[9]  = { w_b2,  Wb2,   64,  0, 64 };
    wb.w[10] = { w_bg2, Wbg2,  64,  0, 64 };
    prep_k<<<dim3(1584 + 2560), dim3(256), 0, stream>>>(wb, x, t, Xpad);

    // --- map conv: h = conv(Xpad, w_map) + b_map ---
    ConvBatch cm{};
    cm.d[0] = { (const uint4*)Xpad, (const uint4*)Wmap, b_map, h, 0 };
    for (int i = 1; i < 6; ++i) cm.d[i] = cm.d[0];
    conv_mfma_k<<<dim3(NIMG, 1, 2), dim3(256), 0, stream>>>(cm);

    // --- stage 1: six convs from h ---
    ConvBatch c1{};
    c1.d[0] = { (const uint4*)h, (const uint4*)Wu1,   b_u1,  p1,    1 };
    c1.d[1] = { (const uint4*)h, (const uint4*)Wug1,  b_ug1, pg1,   1 };
    c1.d[2] = { (const uint4*)h, (const uint4*)Wb1a,  b_b1,  Abuf,  0 };
    c1.d[3] = { (const uint4*)h, (const uint4*)Wb1b,  nullptr, Bbuf, 0 };
    c1.d[4] = { (const uint4*)h, (const uint4*)Wbg1a, b_bg1, Agbuf, 0 };
    c1.d[5] = { (const uint4*)h, (const uint4*)Wbg1b, nullptr, Bgbuf, 0 };
    conv_mfma_k<<<dim3(NIMG, 6, 2), dim3(256), 0, stream>>>(c1);

    // --- stage 2: u_lin, ug_lin (must finish BEFORE pair overwrites p1/pg1) ---
    ConvBatch c2{};
    c2.d[0] = { (const uint4*)p1,  (const uint4*)Wu2,  b_u2,  u_lin,  0 };
    c2.d[1] = { (const uint4*)pg1, (const uint4*)Wug2, b_ug2, ug_lin, 0 };
    for (int i = 2; i < 6; ++i) c2.d[i] = c2.d[0];
    conv_mfma_k<<<dim3(NIMG, 2, 2), dim3(256), 0, stream>>>(c2);

    // --- pairwise messages -> bf16 partial slabs ---
    pair_mfma_k<<<dim3(800), dim3(256), 0, stream>>>(
        (const uint4*)Abuf, (const uint4*)Bbuf, (const uint4*)Agbuf, (const uint4*)Bgbuf,
        (const uint4*)Wb2, (const uint4*)Wbg2, b_b2, b_bg2, partials);

    // --- final combine ---
    final_k<<<dim3(NIMG), dim3(512), 0, stream>>>(u_lin, ug_lin, partials, out);
}

// Round 14
// 82.042 us; speedup vs baseline: 1.3927x; 1.3927x over previous
//
#include <hip/hip_runtime.h>
#include <math.h>

// N=2, K=20 -> 40 images; C=64 channels; 16x16 images (256 px).
#define NIMG 40
#define PXI  256
#define CH   64
#define SB_ELEM (NIMG * PXI * CH)   // 655360 elems per activation tensor
#define ZEROOFF 32768u              // byte offset of zero slot (stage-conv paths)

typedef __bf16 bf16x8 __attribute__((ext_vector_type(8)));
typedef float  f32x4  __attribute__((ext_vector_type(4)));

static __device__ __forceinline__ unsigned short f2bf(float f) {
    unsigned u = __builtin_bit_cast(unsigned, f);
    u += 0x7fffu + ((u >> 16) & 1u);          // RNE
    return (unsigned short)(u >> 16);
}
static __device__ __forceinline__ unsigned cvtpk(float lo, float hi) {
    unsigned r;
    asm("v_cvt_pk_bf16_f32 %0, %1, %2" : "=v"(r) : "v"(lo), "v"(hi));
    return r;
}
static __device__ __forceinline__ float bfu2f(unsigned hs) {  // bf16 bits in low 16
    unsigned u = (hs & 0xffffu) << 16;
    return __builtin_bit_cast(float, u);
}
static __device__ __forceinline__ float sigm(float x) {
    return 1.f / (1.f + __expf(-x));
}

// ===========================================================================
// Weight layout (coalesced): uint4 index = ((kk*2+kh)*4 + oct)*64 + lane;
// element j: oc = oct*16 + (lane&15), ci = (kh*4+(lane>>4))*8 + j.
// LDS Z swizzle: pixel pix, 16B ci-group g at byte pix*128 + ((g^(pix&7))<<4).
//
// WORKSPACE LIVENESS INVARIANT (G16): partials slabs 0..9 overlay
// Xpad/h/p1/pg1; ALL consumers of those (map, stage-1, stage-2 convs) must
// complete in launches BEFORE pair_mfma_k. Do NOT fuse stage-2 into the pair
// kernel (R8/R9 race).
// ===========================================================================

// ---------------------------------------------------------------------------
// Stage-conv core (R6/R7 proven): wave computes R rows x O oc-tiles.
// ---------------------------------------------------------------------------
template<int R, int O>
static __device__ __forceinline__ void conv_core(const char* __restrict__ zb,
                                                 const uint4* __restrict__ Wt,
                                                 int octg0, int r0, int lane,
                                                 const unsigned base[2][3],
                                                 const unsigned step[3],
                                                 f32x4 (&acc)[R][O])
{
#pragma unroll
    for (int kx = 0; kx < 3; ++kx)
#pragma unroll
        for (int kh = 0; kh < 2; ++kh) {
            uint4 w[3][O];
#pragma unroll
            for (int ky = 0; ky < 3; ++ky)
#pragma unroll
                for (int o = 0; o < O; ++o)
                    w[ky][o] = Wt[(((ky * 3 + kx) * 2 + kh) * 4 + octg0 + o) * 64 + lane];
#pragma unroll
            for (int dd = 0; dd < R + 2; ++dd) {
                const int ri = r0 + dd - 1;          // input row (wave-uniform)
                if (ri >= 0 && ri < 16) {
                    uint4 a = *(const uint4*)(zb + (base[kh][kx] + (unsigned)ri * step[kx]));
                    bf16x8 af = __builtin_bit_cast(bf16x8, a);
#pragma unroll
                    for (int ky = 0; ky < 3; ++ky) {
                        const int orow = dd - ky;
                        if (orow < 0 || orow >= R) continue;
#pragma unroll
                        for (int o = 0; o < O; ++o)
                            acc[orow][o] = __builtin_amdgcn_mfma_f32_16x16x32_bf16(
                                af, __builtin_bit_cast(bf16x8, w[ky][o]), acc[orow][o], 0, 0, 0);
                    }
                }
            }
        }
}

static __device__ __forceinline__ void make_base(unsigned base[2][3], unsigned step[3],
                                                 int l15, int l4)
{
#pragma unroll
    for (int kx = 0; kx < 3; ++kx) {
        const int xi = l15 + kx - 1;
        const bool valid = (unsigned)xi < 16u;
        step[kx] = valid ? 2048u : 0u;
#pragma unroll
        for (int kh = 0; kh < 2; ++kh) {
            const int g = kh * 4 + l4;
            base[kh][kx] = valid ? (unsigned)(xi * 128 + (((g ^ (xi & 7))) << 4))
                                 : ZEROOFF;
        }
    }
}

// pair variant: invalid-x lanes read their own center column (2-way conflict
// is free per m136) and get the value AND'ed to zero via xmask. (R11-proven:
// bank conflicts -> 0.)
static __device__ __forceinline__ void make_base_pair(unsigned colbase[2][3], unsigned xmask[3],
                                                      int l15, int l4)
{
#pragma unroll
    for (int kx = 0; kx < 3; ++kx) {
        const int xi = l15 + kx - 1;
        const bool valid = (unsigned)xi < 16u;
        xmask[kx] = valid ? 0xFFFFFFFFu : 0u;
        const int xe = valid ? xi : l15;     // center column is always valid
#pragma unroll
        for (int kh = 0; kh < 2; ++kh) {
            const int g = kh * 4 + l4;
            colbase[kh][kx] = (unsigned)(xe * 128 + (((g ^ (xe & 7))) << 4));
        }
    }
}

// ---------------------------------------------------------------------------
// Stage convs (map + stage1 + stage2): 256 thr = 4 waves, grid (img, desc, half).
// ---------------------------------------------------------------------------
struct ConvDesc {
    const uint4* X;
    const uint4* W;
    const float* bias;      // nullptr -> no bias
    unsigned short* out;
    int relu;
};
struct ConvBatch { ConvDesc d[6]; };

__global__ __launch_bounds__(256)
void conv_mfma_k(ConvBatch cb)
{
    __shared__ uint4 Z[2049];
    const ConvDesc d = cb.d[blockIdx.y];
    const int img = blockIdx.x;
    const int tid = threadIdx.x;

    const uint4* Xi = d.X + img * 2048;
#pragma unroll
    for (int i = 0; i < 8; ++i) {
        int u = i * 256 + tid;
        int px = u >> 3, g = u & 7;
        Z[px * 8 + (g ^ (px & 7))] = Xi[u];
    }
    if (tid == 0) { uint4 z4 = {0u, 0u, 0u, 0u}; Z[2048] = z4; }
    __syncthreads();

    const int lane = tid & 63, wv = tid >> 6;
    const int l15 = lane & 15, l4 = lane >> 4;
    const int rg = wv & 1, op = wv >> 1;
    const int r0 = blockIdx.z * 8 + rg * 4;

    unsigned base[2][3], step[3];
    make_base(base, step, l15, l4);

    f32x4 acc[4][2];
    const f32x4 zz = {0.f, 0.f, 0.f, 0.f};
#pragma unroll
    for (int r = 0; r < 4; ++r)
#pragma unroll
        for (int o = 0; o < 2; ++o) acc[r][o] = zz;

    conv_core<4, 2>((const char*)Z, d.W, op * 2, r0, lane, base, step, acc);

#pragma unroll
    for (int o = 0; o < 2; ++o) {
        const int oc = (op * 2 + o) * 16 + l15;
        const float b = d.bias ? d.bias[oc] : 0.f;
#pragma unroll
        for (int r = 0; r < 4; ++r)
#pragma unroll
            for (int e = 0; e < 4; ++e) {
                float v = acc[r][o][e] + b;
                if (d.relu) v = fmaxf(v, 0.f);
                const int px = (r0 + r) * 16 + l4 * 4 + e;
                d.out[(img * PXI + px) * CH + oc] = f2bf(v);
            }
    }
}

// ---------------------------------------------------------------------------
// Pair dual-source conv, 4-row x 2-oct wave (R14): per (kh,kx) load 6 weight
// frags ONCE, sweep 6 input rows; each row read feeds up to 3 output rows x
// 2 octs x 2 sources. Frag loads/pass: 36 (vs 72 in R12) -> weight L2
// traffic halves. ds_reads and MFMA count unchanged.
// Z0 at slots 0..2047, Z1 at 2048..4095 (imm +32768 on the same address).
// ---------------------------------------------------------------------------
static __device__ __forceinline__ void conv_dual4(const char* __restrict__ zb,
                                                  const uint4* __restrict__ Wt,
                                                  int r0, int octg0, int lane,
                                                  const unsigned colbase[2][3],
                                                  const unsigned xmask[3],
                                                  f32x4 acc[2][4][2])  // [src][row][o]
{
#pragma unroll
    for (int kh = 0; kh < 2; ++kh)
#pragma unroll
        for (int kx = 0; kx < 3; ++kx) {
            bf16x8 wf[3][2];
#pragma unroll
            for (int ky = 0; ky < 3; ++ky)
#pragma unroll
                for (int o = 0; o < 2; ++o)
                    wf[ky][o] = __builtin_bit_cast(bf16x8,
                        Wt[(((ky * 3 + kx) * 2 + kh) * 4 + octg0 + o) * 64 + lane]);
#pragma unroll
            for (int dd = 0; dd < 6; ++dd) {
                const int ri = r0 + dd - 1;          // input row (wave-uniform)
                if (ri >= 0 && ri < 16) {
                    const unsigned addr = colbase[kh][kx] + (unsigned)ri * 2048u;
                    uint4 a0 = *(const uint4*)(zb + addr);
                    uint4 a1 = *(const uint4*)(zb + addr + 32768u);
                    const unsigned m = xmask[kx];
                    a0.x &= m; a0.y &= m; a0.z &= m; a0.w &= m;
                    a1.x &= m; a1.y &= m; a1.z &= m; a1.w &= m;
                    bf16x8 f0 = __builtin_bit_cast(bf16x8, a0);
                    bf16x8 f1 = __builtin_bit_cast(bf16x8, a1);
#pragma unroll
                    for (int ky = 0; ky < 3; ++ky) {
                        const int orow = dd - ky;
                        if (orow < 0 || orow >= 4) continue;
#pragma unroll
                        for (int o = 0; o < 2; ++o) {
                            acc[0][orow][o] = __builtin_amdgcn_mfma_f32_16x16x32_bf16(
                                f0, wf[ky][o], acc[0][orow][o], 0, 0, 0);
                            acc[1][orow][o] = __builtin_amdgcn_mfma_f32_16x16x32_bf16(
                                f1, wf[ky][o], acc[1][orow][o], 0, 0, 0);
                        }
                    }
                }
            }
        }
}

static __device__ __forceinline__ uint4 relu_add4(uint4 a, uint4 b) {
    uint4 o;
    unsigned* ap = &a.x; unsigned* bp = &b.x; unsigned* op2 = &o.x;
#pragma unroll
    for (int w = 0; w < 4; ++w) {
        float a0 = __builtin_bit_cast(float, ap[w] << 16);
        float a1 = __builtin_bit_cast(float, ap[w] & 0xffff0000u);
        float b0 = __builtin_bit_cast(float, bp[w] << 16);
        float b1 = __builtin_bit_cast(float, bp[w] & 0xffff0000u);
        op2[w] = cvtpk(fmaxf(a0 + b0, 0.f), fmaxf(a1 + b1, 0.f));
    }
    return o;
}

// ---------------------------------------------------------------------------
// Pair kernel (grid 400, 512 thr = 8 waves): (imgb, s) dual-source; odd s
// runs the gate pass first (anti-convoy). Wave wv: rg = wv&3 -> rows rg*4..+3,
// op = wv>>2 -> octs op*2..+1. LDS: Z[4096] = 65536 B.
// T14 prefetch of pass-2 globals; T5 setprio around MFMA passes.
// ---------------------------------------------------------------------------
__global__ __launch_bounds__(512)
void pair_mfma_k(const uint4* __restrict__ Abf, const uint4* __restrict__ Bbf,
                 const uint4* __restrict__ Agbf, const uint4* __restrict__ Bgbf,
                 const uint4* __restrict__ W2, const uint4* __restrict__ Wg2,
                 const float* __restrict__ b2, const float* __restrict__ bg2,
                 unsigned short* __restrict__ partials)
{
    __shared__ uint4 Z[4096];
    const char* zb = (const char*)Z;
    const int bx0 = blockIdx.x;
    const int tid = threadIdx.x;
    const int lane = tid & 63, wv = tid >> 6;
    const int l15 = lane & 15, l4 = lane >> 4;
    const int rg = wv & 3, op = wv >> 2;
    const int r0 = rg * 4;

    // XCD-chunked bijective swizzle (400 % 8 == 0)
    const int bi  = (bx0 & 7) * 50 + (bx0 >> 3);
    const int imgb = bi / 10;
    const int s    = bi % 10;
    const int n    = imgb / 20;
    const int gf   = s & 1;                  // gate-first stagger
    const int imga0 = n * 20 + s * 2;

    const uint4* A1; const uint4* B1; const uint4* Wp1;
    const uint4* A2; const uint4* B2; const uint4* Wp2;
    if (!gf) { A1 = Abf  + imgb * 2048; B1 = Bbf  + imga0 * 2048; Wp1 = W2;
               A2 = Agbf + imgb * 2048; B2 = Bgbf + imga0 * 2048; Wp2 = Wg2; }
    else     { A1 = Agbf + imgb * 2048; B1 = Bgbf + imga0 * 2048; Wp1 = Wg2;
               A2 = Abf  + imgb * 2048; B2 = Bbf  + imga0 * 2048; Wp2 = W2; }

    // ---- build pass-1 Z (both sources) ----
#pragma unroll
    for (int i = 0; i < 4; ++i) {
        int u = i * 512 + tid;
        int slot = (u >> 3) * 8 + ((u & 7) ^ ((u >> 3) & 7));
        uint4 a = A1[u];
        Z[slot]        = relu_add4(a, B1[u]);
        Z[2048 + slot] = relu_add4(a, B1[u + 2048]);
    }
    __syncthreads();

    // ---- T14 prefetch: issue pass-2 global loads now (consumed after conv1) ----
    uint4 pfA[4], pfB[4];
#pragma unroll
    for (int i = 0; i < 4; ++i) {
        int u = i * 512 + tid;
        pfA[i] = A2[u];
        pfB[i] = B2[u];
    }

    unsigned colbase[2][3], xmask[3];
    make_base_pair(colbase, xmask, l15, l4);

    const f32x4 zz = {0.f, 0.f, 0.f, 0.f};
    f32x4 acc[2][4][2];
#pragma unroll
    for (int sc = 0; sc < 2; ++sc)
#pragma unroll
        for (int r = 0; r < 4; ++r)
#pragma unroll
            for (int o = 0; o < 2; ++o) acc[sc][r][o] = zz;

    __builtin_amdgcn_s_setprio(1);
    conv_dual4(zb, Wp1, r0, op * 2, lane, colbase, xmask, acc);
    __builtin_amdgcn_s_setprio(0);

    float bmv[2], bgv[2];
#pragma unroll
    for (int o = 0; o < 2; ++o) {
        bmv[o] = b2[(op * 2 + o) * 16 + l15];
        bgv[o] = bg2[(op * 2 + o) * 16 + l15];
    }

    // ---- stash pass-1 result as bf16 ----
    unsigned st[2][4][2][2];
    if (!gf) {
#pragma unroll
        for (int sc = 0; sc < 2; ++sc)
#pragma unroll
            for (int r = 0; r < 4; ++r)
#pragma unroll
                for (int o = 0; o < 2; ++o) {
                    st[sc][r][o][0] = cvtpk(acc[sc][r][o][0] + bmv[o],
                                            acc[sc][r][o][1] + bmv[o]);
                    st[sc][r][o][1] = cvtpk(acc[sc][r][o][2] + bmv[o],
                                            acc[sc][r][o][3] + bmv[o]);
                }
    } else {
#pragma unroll
        for (int sc = 0; sc < 2; ++sc)
#pragma unroll
            for (int r = 0; r < 4; ++r)
#pragma unroll
                for (int o = 0; o < 2; ++o) {
                    st[sc][r][o][0] = cvtpk(sigm(acc[sc][r][o][0] + bgv[o]),
                                            sigm(acc[sc][r][o][1] + bgv[o]));
                    st[sc][r][o][1] = cvtpk(sigm(acc[sc][r][o][2] + bgv[o]),
                                            sigm(acc[sc][r][o][3] + bgv[o]));
                }
    }
    __syncthreads();   // all reads of Z done

    // ---- build pass-2 Z from prefetched registers (+ src1 B loads) ----
#pragma unroll
    for (int i = 0; i < 4; ++i) {
        int u = i * 512 + tid;
        int slot = (u >> 3) * 8 + ((u & 7) ^ ((u >> 3) & 7));
        Z[slot]        = relu_add4(pfA[i], pfB[i]);
        Z[2048 + slot] = relu_add4(pfA[i], B2[u + 2048]);
    }
    __syncthreads();

#pragma unroll
    for (int sc = 0; sc < 2; ++sc)
#pragma unroll
        for (int r = 0; r < 4; ++r)
#pragma unroll
            for (int o = 0; o < 2; ++o) acc[sc][r][o] = zz;

    __builtin_amdgcn_s_setprio(1);
    conv_dual4(zb, Wp2, r0, op * 2, lane, colbase, xmask, acc);
    __builtin_amdgcn_s_setprio(0);

    // ---- combine + store: partials[s][img][oc][px] ----
    const int pbase = (s * NIMG + imgb) * (PXI * CH);
#pragma unroll
    for (int r = 0; r < 4; ++r)
#pragma unroll
        for (int o = 0; o < 2; ++o) {
            float ov[4] = {0.f, 0.f, 0.f, 0.f};
            if (!gf) {
#pragma unroll
                for (int sc = 0; sc < 2; ++sc)
#pragma unroll
                    for (int e = 0; e < 4; ++e) {
                        float gt = acc[sc][r][o][e] + bgv[o];
                        float m  = bfu2f(st[sc][r][o][e >> 1] >> ((e & 1) * 16));
                        ov[e] += m * sigm(gt);
                    }
            } else {
#pragma unroll
                for (int sc = 0; sc < 2; ++sc)
#pragma unroll
                    for (int e = 0; e < 4; ++e) {
                        float m  = acc[sc][r][o][e] + bmv[o];
                        float sg = bfu2f(st[sc][r][o][e >> 1] >> ((e & 1) * 16));
                        ov[e] += m * sg;
                    }
            }
            uint2 pkd;
            pkd.x = cvtpk(ov[0], ov[1]);
            pkd.y = cvtpk(ov[2], ov[3]);
            const int px0 = (r0 + r) * 16 + l4 * 4;
            const int oc  = (op * 2 + o) * 16 + l15;
            *(uint2*)&partials[pbase + oc * PXI + px0] = pkd;
        }
}

// ---------------------------------------------------------------------------
// Merged prep: weight repack (coalesced layout) + X padding.
// ---------------------------------------------------------------------------
struct WPrep { const float* src; unsigned short* dst; int cin_src; int cioff; int nvalid; };
struct WPrepBatch { WPrep w[11]; };

__global__ __launch_bounds__(256)
void prep_k(WPrepBatch wb, const float* __restrict__ x, const float* __restrict__ t,
            unsigned short* __restrict__ Xpad)
{
    const int bx = blockIdx.x;
    if (bx < 1584) {
        const WPrep p = wb.w[bx / 144];
        const int e = (bx % 144) * 256 + threadIdx.x;   // 0..36863
        const int j = e & 7;
        const int u4 = e >> 3;
        const int lane = u4 & 63;
        const int oct = (u4 >> 6) & 3;
        const int kh  = (u4 >> 8) & 1;
        const int kk  = u4 >> 9;
        const int oc  = oct * 16 + (lane & 15);
        const int ci  = (kh * 4 + (lane >> 4)) * 8 + j;
        float v = 0.f;
        if (ci < p.nvalid)
            v = p.src[(oc * p.cin_src + p.cioff + ci) * 9 + kk];
        p.dst[e] = f2bf(v);
    } else {
        const int idx = (bx - 1584) * 256 + threadIdx.x;  // 0..655359
        const int img = idx >> 14;
        const int px  = (idx >> 6) & 255;
        const int ch  = idx & 63;
        float v;
        if (ch == 0)       v = t[0];
        else if (ch <= 32) v = x[((img * 32) + (ch - 1)) * PXI + px];
        else               v = 0.f;
        Xpad[idx] = f2bf(v);
    }
}

// ---------------------------------------------------------------------------
// Final: out[img][oc][px] = u*sigmoid(ug) + (sum_s partials[s])/19.
// ---------------------------------------------------------------------------
__global__ __launch_bounds__(512)
void final_k(const unsigned short* __restrict__ u_lin,
             const unsigned short* __restrict__ ug_lin,
             const unsigned short* __restrict__ P,
             float* __restrict__ out)
{
    __shared__ float buf[PXI * 65];
    const int img = blockIdx.x;
    const int tid = threadIdx.x;

#pragma unroll
    for (int i = 0; i < 32; ++i) {
        const int idx = i * 512 + tid;          // [px][oc], oc innermost
        const int px = idx >> 6, oc = idx & 63;
        const float u = bfu2f(u_lin[img * (PXI * CH) + idx]);
        const float g = bfu2f(ug_lin[img * (PXI * CH) + idx]);
        buf[px * 65 + oc] = u * sigm(g);
    }
    __syncthreads();
#pragma unroll
    for (int i = 0; i < 32; ++i) {
        const int j = i * 512 + tid;            // [oc][px], px innermost
        const int oc = j >> 8, px = j & 255;
        float ssum = 0.f;
#pragma unroll
        for (int sl = 0; sl < 10; ++sl)
            ssum += bfu2f(P[(sl * NIMG + img) * (PXI * CH) + j]);
        out[img * (PXI * CH) + j] = buf[px * 65 + oc] + ssum * (1.f / 19.f);
    }
}

// ---------------------------------------------------------------------------
extern "C" void kernel_launch(void* const* d_in, const int* in_sizes, int n_in,
                              void* d_out, int out_size, void* d_ws, size_t ws_size,
                              hipStream_t stream)
{
    const float* t     = (const float*)d_in[0];
    const float* x     = (const float*)d_in[1];
    const float* w_map = (const float*)d_in[2];
    const float* b_map = (const float*)d_in[3];
    const float* w_u1  = (const float*)d_in[4];
    const float* b_u1  = (const float*)d_in[5];
    const float* w_u2  = (const float*)d_in[6];
    const float* b_u2  = (const float*)d_in[7];
    const float* w_ug1 = (const float*)d_in[8];
    const float* b_ug1 = (const float*)d_in[9];
    const float* w_ug2 = (const float*)d_in[10];
    const float* b_ug2 = (const float*)d_in[11];
    const float* w_b1  = (const float*)d_in[12];
    const float* b_b1  = (const float*)d_in[13];
    const float* w_b2  = (const float*)d_in[14];
    const float* b_b2  = (const float*)d_in[15];
    const float* w_bg1 = (const float*)d_in[16];
    const float* b_bg1 = (const float*)d_in[17];
    const float* w_bg2 = (const float*)d_in[18];
    const float* b_bg2 = (const float*)d_in[19];

    float* out = (float*)d_out;
    char* ws = (char*)d_ws;

    const size_t ABYTES = (size_t)SB_ELEM * 2;      // 1,310,720 B per bf16 tensor

    // Partials (10 bf16 slabs) overlay slabs 0..9; Xpad/h/p1/pg1 live in the
    // first 4 and are dead before pair_mfma_k runs (ALL their consumers --
    // map, stage-1, stage-2 -- are in earlier launches; see invariant above).
    unsigned short* partials = (unsigned short*)(ws);
    unsigned short* Xpad   = (unsigned short*)(ws + 0 * ABYTES);
    unsigned short* h      = (unsigned short*)(ws + 1 * ABYTES);
    unsigned short* p1     = (unsigned short*)(ws + 2 * ABYTES);
    unsigned short* pg1    = (unsigned short*)(ws + 3 * ABYTES);
    unsigned short* u_lin  = (unsigned short*)(ws + 10 * ABYTES);
    unsigned short* ug_lin = (unsigned short*)(ws + 11 * ABYTES);
    unsigned short* Abuf   = (unsigned short*)(ws + 12 * ABYTES);
    unsigned short* Bbuf   = (unsigned short*)(ws + 13 * ABYTES);
    unsigned short* Agbuf  = (unsigned short*)(ws + 14 * ABYTES);
    unsigned short* Bgbuf  = (unsigned short*)(ws + 15 * ABYTES);
    char* wbase = ws + 16 * ABYTES;                 // ~21 MB
    const size_t WBYTES = 9 * 64 * 64 * 2;          // 73,728 B per weight tensor
    unsigned short* Wmap  = (unsigned short*)(wbase + 0 * WBYTES);
    unsigned short* Wu1   = (unsigned short*)(wbase + 1 * WBYTES);
    unsigned short* Wu2   = (unsigned short*)(wbase + 2 * WBYTES);
    unsigned short* Wug1  = (unsigned short*)(wbase + 3 * WBYTES);
    unsigned short* Wug2  = (unsigned short*)(wbase + 4 * WBYTES);
    unsigned short* Wb1a  = (unsigned short*)(wbase + 5 * WBYTES);
    unsigned short* Wb1b  = (unsigned short*)(wbase + 6 * WBYTES);
    unsigned short* Wbg1a = (unsigned short*)(wbase + 7 * WBYTES);
    unsigned short* Wbg1b = (unsigned short*)(wbase + 8 * WBYTES);
    unsigned short* Wb2   = (unsigned short*)(wbase + 9 * WBYTES);
    unsigned short* Wbg2  = (unsigned short*)(wbase + 10 * WBYTES);

    // --- prep: weights repack + Xpad build (one launch) ---
    WPrepBatch wb;
    wb.w[0]  = { w_map, Wmap,  33,  0, 33 };
    wb.w[1]  = { w_u1,  Wu1,   64,  0, 64 };
    wb.w[2]  = { w_u2,  Wu2,   64,  0, 64 };
    wb.w[3]  = { w_ug1, Wug1,  64,  0, 64 };
    wb.w[4]  = { w_ug2, Wug2,  64,  0, 64 };
    wb.w[5]  = { w_b1,  Wb1a, 128,  0, 64 };
    wb.w[6]  = { w_b1,  Wb1b, 128, 64, 64 };
    wb.w[7]  = { w_bg1, Wbg1a,128,  0, 64 };
    wb.w[8]  = { w_bg1, Wbg1b,128, 64, 64 };
    wb.w[9]  = { w_b2,  Wb2,   64,  0, 64 };
    wb.w[10] = { w_bg2, Wbg2,  64,  0, 64 };
    prep_k<<<dim3(1584 + 2560), dim3(256), 0, stream>>>(wb, x, t, Xpad);

    // --- map conv: h = conv(Xpad, w_map) + b_map ---
    ConvBatch cm{};
    cm.d[0] = { (const uint4*)Xpad, (const uint4*)Wmap, b_map, h, 0 };
    for (int i = 1; i < 6; ++i) cm.d[i] = cm.d[0];
    conv_mfma_k<<<dim3(NIMG, 1, 2), dim3(256), 0, stream>>>(cm);

    // --- stage 1: six convs from h ---
    ConvBatch c1{};
    c1.d[0] = { (const uint4*)h, (const uint4*)Wu1,   b_u1,  p1,    1 };
    c1.d[1] = { (const uint4*)h, (const uint4*)Wug1,  b_ug1, pg1,   1 };
    c1.d[2] = { (const uint4*)h, (const uint4*)Wb1a,  b_b1,  Abuf,  0 };
    c1.d[3] = { (const uint4*)h, (const uint4*)Wb1b,  nullptr, Bbuf, 0 };
    c1.d[4] = { (const uint4*)h, (const uint4*)Wbg1a, b_bg1, Agbuf, 0 };
    c1.d[5] = { (const uint4*)h, (const uint4*)Wbg1b, nullptr, Bgbuf, 0 };
    conv_mfma_k<<<dim3(NIMG, 6, 2), dim3(256), 0, stream>>>(c1);

    // --- stage 2: u_lin, ug_lin (must finish BEFORE pair overwrites p1/pg1) ---
    ConvBatch c2{};
    c2.d[0] = { (const uint4*)p1,  (const uint4*)Wu2,  b_u2,  u_lin,  0 };
    c2.d[1] = { (const uint4*)pg1, (const uint4*)Wug2, b_ug2, ug_lin, 0 };
    for (int i = 2; i < 6; ++i) c2.d[i] = c2.d[0];
    conv_mfma_k<<<dim3(NIMG, 2, 2), dim3(256), 0, stream>>>(c2);

    // --- pairwise messages -> bf16 partial slabs ---
    pair_mfma_k<<<dim3(400), dim3(512), 0, stream>>>(
        (const uint4*)Abuf, (const uint4*)Bbuf, (const uint4*)Agbuf, (const uint4*)Bgbuf,
        (const uint4*)Wb2, (const uint4*)Wbg2, b_b2, b_bg2, partials);

    // --- final combine ---
    final_k<<<dim3(NIMG), dim3(512), 0, stream>>>(u_lin, ug_lin, partials, out);
}

// Round 15
// 81.492 us; speedup vs baseline: 1.4021x; 1.0067x over previous
//
#include <hip/hip_runtime.h>
#include <math.h>

// N=2, K=20 -> 40 images; C=64 channels; 16x16 images (256 px).
#define NIMG 40
#define PXI  256
#define CH   64
#define SB_ELEM (NIMG * PXI * CH)   // 655360 elems per activation tensor
#define ZEROOFF 32768u              // byte offset of zero slot (stage-conv paths)

typedef __bf16 bf16x8 __attribute__((ext_vector_type(8)));
typedef float  f32x4  __attribute__((ext_vector_type(4)));

static __device__ __forceinline__ unsigned short f2bf(float f) {
    unsigned u = __builtin_bit_cast(unsigned, f);
    u += 0x7fffu + ((u >> 16) & 1u);          // RNE
    return (unsigned short)(u >> 16);
}
static __device__ __forceinline__ unsigned cvtpk(float lo, float hi) {
    unsigned r;
    asm("v_cvt_pk_bf16_f32 %0, %1, %2" : "=v"(r) : "v"(lo), "v"(hi));
    return r;
}
static __device__ __forceinline__ float bfu2f(unsigned hs) {  // bf16 bits in low 16
    unsigned u = (hs & 0xffffu) << 16;
    return __builtin_bit_cast(float, u);
}
static __device__ __forceinline__ float sigm(float x) {
    return 1.f / (1.f + __expf(-x));
}

// ===========================================================================
// Weight layout (coalesced): uint4 index = ((kk*2+kh)*4 + oct)*64 + lane;
// element j: oc = oct*16 + (lane&15), ci = (kh*4+(lane>>4))*8 + j.
// LDS Z swizzle: pixel pix, 16B ci-group g at byte pix*128 + ((g^(pix&7))<<4).
//
// WORKSPACE LIVENESS INVARIANT (G16): partials slabs 0..9 overlay
// Xpad/h/p1/pg1; ALL consumers of those (map, stage-1, stage-2 convs) must
// complete in launches BEFORE pair_mfma_k. Do NOT fuse stage-2 into the pair
// kernel (R8/R9 race).
//
// Constraint surface (R8..R14 measured): static LDS <= 65536 B (R8);
// VGPR <= 128 for 4 waves/SIMD (R5/R13 spills); dual-source full-image Z
// (64KB) -> 2 blocks/CU; 4-row x 2-oct x 2-src wave = best MFMA-per-LDS-read
// (R11/R13 smaller tiles regressed).
// ===========================================================================

// ---------------------------------------------------------------------------
// Stage-conv core (R6/R7 proven): wave computes R rows x O oc-tiles.
// ---------------------------------------------------------------------------
template<int R, int O>
static __device__ __forceinline__ void conv_core(const char* __restrict__ zb,
                                                 const uint4* __restrict__ Wt,
                                                 int octg0, int r0, int lane,
                                                 const unsigned base[2][3],
                                                 const unsigned step[3],
                                                 f32x4 (&acc)[R][O])
{
#pragma unroll
    for (int kx = 0; kx < 3; ++kx)
#pragma unroll
        for (int kh = 0; kh < 2; ++kh) {
            uint4 w[3][O];
#pragma unroll
            for (int ky = 0; ky < 3; ++ky)
#pragma unroll
                for (int o = 0; o < O; ++o)
                    w[ky][o] = Wt[(((ky * 3 + kx) * 2 + kh) * 4 + octg0 + o) * 64 + lane];
#pragma unroll
            for (int dd = 0; dd < R + 2; ++dd) {
                const int ri = r0 + dd - 1;          // input row (wave-uniform)
                if (ri >= 0 && ri < 16) {
                    uint4 a = *(const uint4*)(zb + (base[kh][kx] + (unsigned)ri * step[kx]));
                    bf16x8 af = __builtin_bit_cast(bf16x8, a);
#pragma unroll
                    for (int ky = 0; ky < 3; ++ky) {
                        const int orow = dd - ky;
                        if (orow < 0 || orow >= R) continue;
#pragma unroll
                        for (int o = 0; o < O; ++o)
                            acc[orow][o] = __builtin_amdgcn_mfma_f32_16x16x32_bf16(
                                af, __builtin_bit_cast(bf16x8, w[ky][o]), acc[orow][o], 0, 0, 0);
                    }
                }
            }
        }
}

static __device__ __forceinline__ void make_base(unsigned base[2][3], unsigned step[3],
                                                 int l15, int l4)
{
#pragma unroll
    for (int kx = 0; kx < 3; ++kx) {
        const int xi = l15 + kx - 1;
        const bool valid = (unsigned)xi < 16u;
        step[kx] = valid ? 2048u : 0u;
#pragma unroll
        for (int kh = 0; kh < 2; ++kh) {
            const int g = kh * 4 + l4;
            base[kh][kx] = valid ? (unsigned)(xi * 128 + (((g ^ (xi & 7))) << 4))
                                 : ZEROOFF;
        }
    }
}

// pair variant: invalid-x lanes read their own center column (2-way conflict
// is free per m136) and get the value AND'ed to zero via xmask. (R11-proven:
// bank conflicts -> 0.)
static __device__ __forceinline__ void make_base_pair(unsigned colbase[2][3], unsigned xmask[3],
                                                      int l15, int l4)
{
#pragma unroll
    for (int kx = 0; kx < 3; ++kx) {
        const int xi = l15 + kx - 1;
        const bool valid = (unsigned)xi < 16u;
        xmask[kx] = valid ? 0xFFFFFFFFu : 0u;
        const int xe = valid ? xi : l15;     // center column is always valid
#pragma unroll
        for (int kh = 0; kh < 2; ++kh) {
            const int g = kh * 4 + l4;
            colbase[kh][kx] = (unsigned)(xe * 128 + (((g ^ (xe & 7))) << 4));
        }
    }
}

// ---------------------------------------------------------------------------
// Stage convs (map + stage1 + stage2): 256 thr = 4 waves, grid (img, desc, half).
// ---------------------------------------------------------------------------
struct ConvDesc {
    const uint4* X;
    const uint4* W;
    const float* bias;      // nullptr -> no bias
    unsigned short* out;
    int relu;
};
struct ConvBatch { ConvDesc d[6]; };

__global__ __launch_bounds__(256)
void conv_mfma_k(ConvBatch cb)
{
    __shared__ uint4 Z[2049];
    const ConvDesc d = cb.d[blockIdx.y];
    const int img = blockIdx.x;
    const int tid = threadIdx.x;

    const uint4* Xi = d.X + img * 2048;
#pragma unroll
    for (int i = 0; i < 8; ++i) {
        int u = i * 256 + tid;
        int px = u >> 3, g = u & 7;
        Z[px * 8 + (g ^ (px & 7))] = Xi[u];
    }
    if (tid == 0) { uint4 z4 = {0u, 0u, 0u, 0u}; Z[2048] = z4; }
    __syncthreads();

    const int lane = tid & 63, wv = tid >> 6;
    const int l15 = lane & 15, l4 = lane >> 4;
    const int rg = wv & 1, op = wv >> 1;
    const int r0 = blockIdx.z * 8 + rg * 4;

    unsigned base[2][3], step[3];
    make_base(base, step, l15, l4);

    f32x4 acc[4][2];
    const f32x4 zz = {0.f, 0.f, 0.f, 0.f};
#pragma unroll
    for (int r = 0; r < 4; ++r)
#pragma unroll
        for (int o = 0; o < 2; ++o) acc[r][o] = zz;

    conv_core<4, 2>((const char*)Z, d.W, op * 2, r0, lane, base, step, acc);

#pragma unroll
    for (int o = 0; o < 2; ++o) {
        const int oc = (op * 2 + o) * 16 + l15;
        const float b = d.bias ? d.bias[oc] : 0.f;
#pragma unroll
        for (int r = 0; r < 4; ++r)
#pragma unroll
            for (int e = 0; e < 4; ++e) {
                float v = acc[r][o][e] + b;
                if (d.relu) v = fmaxf(v, 0.f);
                const int px = (r0 + r) * 16 + l4 * 4 + e;
                d.out[(img * PXI + px) * CH + oc] = f2bf(v);
            }
    }
}

// ---------------------------------------------------------------------------
// Pair dual-source conv, 4-row x 2-oct wave (R14): per (kh,kx) load 6 weight
// frags ONCE, sweep 6 input rows; each row read feeds up to 3 output rows x
// 2 octs x 2 sources. Center tap (kx==1) skips the border value-AND (always
// valid). Z0 at slots 0..2047, Z1 at 2048..4095 (imm +32768 offset).
// ---------------------------------------------------------------------------
static __device__ __forceinline__ void conv_dual4(const char* __restrict__ zb,
                                                  const uint4* __restrict__ Wt,
                                                  int r0, int octg0, int lane,
                                                  const unsigned colbase[2][3],
                                                  const unsigned xmask[3],
                                                  f32x4 acc[2][4][2])  // [src][row][o]
{
#pragma unroll
    for (int kh = 0; kh < 2; ++kh)
#pragma unroll
        for (int kx = 0; kx < 3; ++kx) {
            bf16x8 wf[3][2];
#pragma unroll
            for (int ky = 0; ky < 3; ++ky)
#pragma unroll
                for (int o = 0; o < 2; ++o)
                    wf[ky][o] = __builtin_bit_cast(bf16x8,
                        Wt[(((ky * 3 + kx) * 2 + kh) * 4 + octg0 + o) * 64 + lane]);
#pragma unroll
            for (int dd = 0; dd < 6; ++dd) {
                const int ri = r0 + dd - 1;          // input row (wave-uniform)
                if (ri >= 0 && ri < 16) {
                    const unsigned addr = colbase[kh][kx] + (unsigned)ri * 2048u;
                    uint4 a0 = *(const uint4*)(zb + addr);
                    uint4 a1 = *(const uint4*)(zb + addr + 32768u);
                    if (kx != 1) {                   // center tap always valid
                        const unsigned m = xmask[kx];
                        a0.x &= m; a0.y &= m; a0.z &= m; a0.w &= m;
                        a1.x &= m; a1.y &= m; a1.z &= m; a1.w &= m;
                    }
                    bf16x8 f0 = __builtin_bit_cast(bf16x8, a0);
                    bf16x8 f1 = __builtin_bit_cast(bf16x8, a1);
#pragma unroll
                    for (int ky = 0; ky < 3; ++ky) {
                        const int orow = dd - ky;
                        if (orow < 0 || orow >= 4) continue;
#pragma unroll
                        for (int o = 0; o < 2; ++o) {
                            acc[0][orow][o] = __builtin_amdgcn_mfma_f32_16x16x32_bf16(
                                f0, wf[ky][o], acc[0][orow][o], 0, 0, 0);
                            acc[1][orow][o] = __builtin_amdgcn_mfma_f32_16x16x32_bf16(
                                f1, wf[ky][o], acc[1][orow][o], 0, 0, 0);
                        }
                    }
                }
            }
        }
}

static __device__ __forceinline__ uint4 relu_add4(uint4 a, uint4 b) {
    uint4 o;
    unsigned* ap = &a.x; unsigned* bp = &b.x; unsigned* op2 = &o.x;
#pragma unroll
    for (int w = 0; w < 4; ++w) {
        float a0 = __builtin_bit_cast(float, ap[w] << 16);
        float a1 = __builtin_bit_cast(float, ap[w] & 0xffff0000u);
        float b0 = __builtin_bit_cast(float, bp[w] << 16);
        float b1 = __builtin_bit_cast(float, bp[w] & 0xffff0000u);
        op2[w] = cvtpk(fmaxf(a0 + b0, 0.f), fmaxf(a1 + b1, 0.f));
    }
    return o;
}

// ---------------------------------------------------------------------------
// Pair kernel (grid 400, 512 thr = 8 waves): (imgb, s) dual-source; odd s
// runs the gate pass first (anti-convoy). Wave wv: rg = wv&3 -> rows rg*4..+3,
// op = wv>>2 -> octs op*2..+1. LDS: Z[4096] = 65536 B.
// R15: no prefetch (R12 null, -32 VGPR), no setprio (m190: null/neg on
// lockstep structures), center-tap mask skip.
// ---------------------------------------------------------------------------
__global__ __launch_bounds__(512)
void pair_mfma_k(const uint4* __restrict__ Abf, const uint4* __restrict__ Bbf,
                 const uint4* __restrict__ Agbf, const uint4* __restrict__ Bgbf,
                 const uint4* __restrict__ W2, const uint4* __restrict__ Wg2,
                 const float* __restrict__ b2, const float* __restrict__ bg2,
                 unsigned short* __restrict__ partials)
{
    __shared__ uint4 Z[4096];
    const char* zb = (const char*)Z;
    const int bx0 = blockIdx.x;
    const int tid = threadIdx.x;
    const int lane = tid & 63, wv = tid >> 6;
    const int l15 = lane & 15, l4 = lane >> 4;
    const int rg = wv & 3, op = wv >> 2;
    const int r0 = rg * 4;

    // XCD-chunked bijective swizzle (400 % 8 == 0)
    const int bi  = (bx0 & 7) * 50 + (bx0 >> 3);
    const int imgb = bi / 10;
    const int s    = bi % 10;
    const int n    = imgb / 20;
    const int gf   = s & 1;                  // gate-first stagger
    const int imga0 = n * 20 + s * 2;

    const uint4* A1; const uint4* B1; const uint4* Wp1;
    const uint4* A2; const uint4* B2; const uint4* Wp2;
    if (!gf) { A1 = Abf  + imgb * 2048; B1 = Bbf  + imga0 * 2048; Wp1 = W2;
               A2 = Agbf + imgb * 2048; B2 = Bgbf + imga0 * 2048; Wp2 = Wg2; }
    else     { A1 = Agbf + imgb * 2048; B1 = Bgbf + imga0 * 2048; Wp1 = Wg2;
               A2 = Abf  + imgb * 2048; B2 = Bbf  + imga0 * 2048; Wp2 = W2; }

    unsigned colbase[2][3], xmask[3];
    make_base_pair(colbase, xmask, l15, l4);

    float bmv[2], bgv[2];
#pragma unroll
    for (int o = 0; o < 2; ++o) {
        bmv[o] = b2[(op * 2 + o) * 16 + l15];
        bgv[o] = bg2[(op * 2 + o) * 16 + l15];
    }

    // ---- build pass-1 Z (both sources) ----
#pragma unroll
    for (int i = 0; i < 4; ++i) {
        int u = i * 512 + tid;
        int slot = (u >> 3) * 8 + ((u & 7) ^ ((u >> 3) & 7));
        uint4 a = A1[u];
        Z[slot]        = relu_add4(a, B1[u]);
        Z[2048 + slot] = relu_add4(a, B1[u + 2048]);
    }
    __syncthreads();

    const f32x4 zz = {0.f, 0.f, 0.f, 0.f};
    f32x4 acc[2][4][2];
#pragma unroll
    for (int sc = 0; sc < 2; ++sc)
#pragma unroll
        for (int r = 0; r < 4; ++r)
#pragma unroll
            for (int o = 0; o < 2; ++o) acc[sc][r][o] = zz;

    conv_dual4(zb, Wp1, r0, op * 2, lane, colbase, xmask, acc);

    // ---- stash pass-1 result as bf16 ----
    unsigned st[2][4][2][2];
    if (!gf) {
#pragma unroll
        for (int sc = 0; sc < 2; ++sc)
#pragma unroll
            for (int r = 0; r < 4; ++r)
#pragma unroll
                for (int o = 0; o < 2; ++o) {
                    st[sc][r][o][0] = cvtpk(acc[sc][r][o][0] + bmv[o],
                                            acc[sc][r][o][1] + bmv[o]);
                    st[sc][r][o][1] = cvtpk(acc[sc][r][o][2] + bmv[o],
                                            acc[sc][r][o][3] + bmv[o]);
                }
    } else {
#pragma unroll
        for (int sc = 0; sc < 2; ++sc)
#pragma unroll
            for (int r = 0; r < 4; ++r)
#pragma unroll
                for (int o = 0; o < 2; ++o) {
                    st[sc][r][o][0] = cvtpk(sigm(acc[sc][r][o][0] + bgv[o]),
                                            sigm(acc[sc][r][o][1] + bgv[o]));
                    st[sc][r][o][1] = cvtpk(sigm(acc[sc][r][o][2] + bgv[o]),
                                            sigm(acc[sc][r][o][3] + bgv[o]));
                }
    }
    __syncthreads();   // all reads of Z done

    // ---- build pass-2 Z ----
#pragma unroll
    for (int i = 0; i < 4; ++i) {
        int u = i * 512 + tid;
        int slot = (u >> 3) * 8 + ((u & 7) ^ ((u >> 3) & 7));
        uint4 a = A2[u];
        Z[slot]        = relu_add4(a, B2[u]);
        Z[2048 + slot] = relu_add4(a, B2[u + 2048]);
    }
    __syncthreads();

#pragma unroll
    for (int sc = 0; sc < 2; ++sc)
#pragma unroll
        for (int r = 0; r < 4; ++r)
#pragma unroll
            for (int o = 0; o < 2; ++o) acc[sc][r][o] = zz;

    conv_dual4(zb, Wp2, r0, op * 2, lane, colbase, xmask, acc);

    // ---- combine + store: partials[s][img][oc][px] ----
    const int pbase = (s * NIMG + imgb) * (PXI * CH);
#pragma unroll
    for (int r = 0; r < 4; ++r)
#pragma unroll
        for (int o = 0; o < 2; ++o) {
            float ov[4] = {0.f, 0.f, 0.f, 0.f};
            if (!gf) {
#pragma unroll
                for (int sc = 0; sc < 2; ++sc)
#pragma unroll
                    for (int e = 0; e < 4; ++e) {
                        float gt = acc[sc][r][o][e] + bgv[o];
                        float m  = bfu2f(st[sc][r][o][e >> 1] >> ((e & 1) * 16));
                        ov[e] += m * sigm(gt);
                    }
            } else {
#pragma unroll
                for (int sc = 0; sc < 2; ++sc)
#pragma unroll
                    for (int e = 0; e < 4; ++e) {
                        float m  = acc[sc][r][o][e] + bmv[o];
                        float sg = bfu2f(st[sc][r][o][e >> 1] >> ((e & 1) * 16));
                        ov[e] += m * sg;
                    }
            }
            uint2 pkd;
            pkd.x = cvtpk(ov[0], ov[1]);
            pkd.y = cvtpk(ov[2], ov[3]);
            const int px0 = (r0 + r) * 16 + l4 * 4;
            const int oc  = (op * 2 + o) * 16 + l15;
            *(uint2*)&partials[pbase + oc * PXI + px0] = pkd;
        }
}

// ---------------------------------------------------------------------------
// Merged prep: weight repack (coalesced layout) + X padding.
// ---------------------------------------------------------------------------
struct WPrep { const float* src; unsigned short* dst; int cin_src; int cioff; int nvalid; };
struct WPrepBatch { WPrep w[11]; };

__global__ __launch_bounds__(256)
void prep_k(WPrepBatch wb, const float* __restrict__ x, const float* __restrict__ t,
            unsigned short* __restrict__ Xpad)
{
    const int bx = blockIdx.x;
    if (bx < 1584) {
        const WPrep p = wb.w[bx / 144];
        const int e = (bx % 144) * 256 + threadIdx.x;   // 0..36863
        const int j = e & 7;
        const int u4 = e >> 3;
        const int lane = u4 & 63;
        const int oct = (u4 >> 6) & 3;
        const int kh  = (u4 >> 8) & 1;
        const int kk  = u4 >> 9;
        const int oc  = oct * 16 + (lane & 15);
        const int ci  = (kh * 4 + (lane >> 4)) * 8 + j;
        float v = 0.f;
        if (ci < p.nvalid)
            v = p.src[(oc * p.cin_src + p.cioff + ci) * 9 + kk];
        p.dst[e] = f2bf(v);
    } else {
        const int idx = (bx - 1584) * 256 + threadIdx.x;  // 0..655359
        const int img = idx >> 14;
        const int px  = (idx >> 6) & 255;
        const int ch  = idx & 63;
        float v;
        if (ch == 0)       v = t[0];
        else if (ch <= 32) v = x[((img * 32) + (ch - 1)) * PXI + px];
        else               v = 0.f;
        Xpad[idx] = f2bf(v);
    }
}

// ---------------------------------------------------------------------------
// Final: out[img][oc][px] = u*sigmoid(ug) + (sum_s partials[s])/19.
// ---------------------------------------------------------------------------
__global__ __launch_bounds__(512)
void final_k(const unsigned short* __restrict__ u_lin,
             const unsigned short* __restrict__ ug_lin,
             const unsigned short* __restrict__ P,
             float* __restrict__ out)
{
    __shared__ float buf[PXI * 65];
    const int img = blockIdx.x;
    const int tid = threadIdx.x;

#pragma unroll
    for (int i = 0; i < 32; ++i) {
        const int idx = i * 512 + tid;          // [px][oc], oc innermost
        const int px = idx >> 6, oc = idx & 63;
        const float u = bfu2f(u_lin[img * (PXI * CH) + idx]);
        const float g = bfu2f(ug_lin[img * (PXI * CH) + idx]);
        buf[px * 65 + oc] = u * sigm(g);
    }
    __syncthreads();
#pragma unroll
    for (int i = 0; i < 32; ++i) {
        const int j = i * 512 + tid;            // [oc][px], px innermost
        const int oc = j >> 8, px = j & 255;
        float ssum = 0.f;
#pragma unroll
        for (int sl = 0; sl < 10; ++sl)
            ssum += bfu2f(P[(sl * NIMG + img) * (PXI * CH) + j]);
        out[img * (PXI * CH) + j] = buf[px * 65 + oc] + ssum * (1.f / 19.f);
    }
}

// ---------------------------------------------------------------------------
extern "C" void kernel_launch(void* const* d_in, const int* in_sizes, int n_in,
                              void* d_out, int out_size, void* d_ws, size_t ws_size,
                              hipStream_t stream)
{
    const float* t     = (const float*)d_in[0];
    const float* x     = (const float*)d_in[1];
    const float* w_map = (const float*)d_in[2];
    const float* b_map = (const float*)d_in[3];
    const float* w_u1  = (const float*)d_in[4];
    const float* b_u1  = (const float*)d_in[5];
    const float* w_u2  = (const float*)d_in[6];
    const float* b_u2  = (const float*)d_in[7];
    const float* w_ug1 = (const float*)d_in[8];
    const float* b_ug1 = (const float*)d_in[9];
    const float* w_ug2 = (const float*)d_in[10];
    const float* b_ug2 = (const float*)d_in[11];
    const float* w_b1  = (const float*)d_in[12];
    const float* b_b1  = (const float*)d_in[13];
    const float* w_b2  = (const float*)d_in[14];
    const float* b_b2  = (const float*)d_in[15];
    const float* w_bg1 = (const float*)d_in[16];
    const float* b_bg1 = (const float*)d_in[17];
    const float* w_bg2 = (const float*)d_in[18];
    const float* b_bg2 = (const float*)d_in[19];

    float* out = (float*)d_out;
    char* ws = (char*)d_ws;

    const size_t ABYTES = (size_t)SB_ELEM * 2;      // 1,310,720 B per bf16 tensor

    // Partials (10 bf16 slabs) overlay slabs 0..9; Xpad/h/p1/pg1 live in the
    // first 4 and are dead before pair_mfma_k runs (ALL their consumers --
    // map, stage-1, stage-2 -- are in earlier launches; see invariant above).
    unsigned short* partials = (unsigned short*)(ws);
    unsigned short* Xpad   = (unsigned short*)(ws + 0 * ABYTES);
    unsigned short* h      = (unsigned short*)(ws + 1 * ABYTES);
    unsigned short* p1     = (unsigned short*)(ws + 2 * ABYTES);
    unsigned short* pg1    = (unsigned short*)(ws + 3 * ABYTES);
    unsigned short* u_lin  = (unsigned short*)(ws + 10 * ABYTES);
    unsigned short* ug_lin = (unsigned short*)(ws + 11 * ABYTES);
    unsigned short* Abuf   = (unsigned short*)(ws + 12 * ABYTES);
    unsigned short* Bbuf   = (unsigned short*)(ws + 13 * ABYTES);
    unsigned short* Agbuf  = (unsigned short*)(ws + 14 * ABYTES);
    unsigned short* Bgbuf  = (unsigned short*)(ws + 15 * ABYTES);
    char* wbase = ws + 16 * ABYTES;                 // ~21 MB
    const size_t WBYTES = 9 * 64 * 64 * 2;          // 73,728 B per weight tensor
    unsigned short* Wmap  = (unsigned short*)(wbase + 0 * WBYTES);
    unsigned short* Wu1   = (unsigned short*)(wbase + 1 * WBYTES);
    unsigned short* Wu2   = (unsigned short*)(wbase + 2 * WBYTES);
    unsigned short* Wug1  = (unsigned short*)(wbase + 3 * WBYTES);
    unsigned short* Wug2  = (unsigned short*)(wbase + 4 * WBYTES);
    unsigned short* Wb1a  = (unsigned short*)(wbase + 5 * WBYTES);
    unsigned short* Wb1b  = (unsigned short*)(wbase + 6 * WBYTES);
    unsigned short* Wbg1a = (unsigned short*)(wbase + 7 * WBYTES);
    unsigned short* Wbg1b = (unsigned short*)(wbase + 8 * WBYTES);
    unsigned short* Wb2   = (unsigned short*)(wbase + 9 * WBYTES);
    unsigned short* Wbg2  = (unsigned short*)(wbase + 10 * WBYTES);

    // --- prep: weights repack + Xpad build (one launch) ---
    WPrepBatch wb;
    wb.w[0]  = { w_map, Wmap,  33,  0, 33 };
    wb.w[1]  = { w_u1,  Wu1,   64,  0, 64 };
    wb.w[2]  = { w_u2,  Wu2,   64,  0, 64 };
    wb.w[3]  = { w_ug1, Wug1,  64,  0, 64 };
    wb.w[4]  = { w_ug2, Wug2,  64,  0, 64 };
    wb.w[5]  = { w_b1,  Wb1a, 128,  0, 64 };
    wb.w[6]  = { w_b1,  Wb1b, 128, 64, 64 };
    wb.w[7]  = { w_bg1, Wbg1a,128,  0, 64 };
    wb.w[8]  = { w_bg1, Wbg1b,128, 64, 64 };
    wb.w[9]  = { w_b2,  Wb2,   64,  0, 64 };
    wb.w[10] = { w_bg2, Wbg2,  64,  0, 64 };
    prep_k<<<dim3(1584 + 2560), dim3(256), 0, stream>>>(wb, x, t, Xpad);

    // --- map conv: h = conv(Xpad, w_map) + b_map ---
    ConvBatch cm{};
    cm.d[0] = { (const uint4*)Xpad, (const uint4*)Wmap, b_map, h, 0 };
    for (int i = 1; i < 6; ++i) cm.d[i] = cm.d[0];
    conv_mfma_k<<<dim3(NIMG, 1, 2), dim3(256), 0, stream>>>(cm);

    // --- stage 1: six convs from h ---
    ConvBatch c1{};
    c1.d[0] = { (const uint4*)h, (const uint4*)Wu1,   b_u1,  p1,    1 };
    c1.d[1] = { (const uint4*)h, (const uint4*)Wug1,  b_ug1, pg1,   1 };
    c1.d[2] = { (const uint4*)h, (const uint4*)Wb1a,  b_b1,  Abuf,  0 };
    c1.d[3] = { (const uint4*)h, (const uint4*)Wb1b,  nullptr, Bbuf, 0 };
    c1.d[4] = { (const uint4*)h, (const uint4*)Wbg1a, b_bg1, Agbuf, 0 };
    c1.d[5] = { (const uint4*)h, (const uint4*)Wbg1b, nullptr, Bgbuf, 0 };
    conv_mfma_k<<<dim3(NIMG, 6, 2), dim3(256), 0, stream>>>(c1);

    // --- stage 2: u_lin, ug_lin (must finish BEFORE pair overwrites p1/pg1) ---
    ConvBatch c2{};
    c2.d[0] = { (const uint4*)p1,  (const uint4*)Wu2,  b_u2,  u_lin,  0 };
    c2.d[1] = { (const uint4*)pg1, (const uint4*)Wug2, b_ug2, ug_lin, 0 };
    for (int i = 2; i < 6; ++i) c2.d[i] = c2.d[0];
    conv_mfma_k<<<dim3(NIMG, 2, 2), dim3(256), 0, stream>>>(c2);

    // --- pairwise messages -> bf16 partial slabs ---
    pair_mfma_k<<<dim3(400), dim3(512), 0, stream>>>(
        (const uint4*)Abuf, (const uint4*)Bbuf, (const uint4*)Agbuf, (const uint4*)Bgbuf,
        (const uint4*)Wb2, (const uint4*)Wbg2, b_b2, b_bg2, partials);

    // --- final combine ---
    final_k<<<dim3(NIMG), dim3(512), 0, stream>>>(u_lin, ug_lin, partials, out);
}